// Round 7
// baseline (559.440 us; speedup 1.0000x reference)
//
#include <hip/hip_runtime.h>
#include <cmath>

// Problem constants
#define Bn 4
#define Sn 2048
#define En 256
#define Hn 8
#define Dn 32
#define KD 256          // inner GEMM dim (= En)

static constexpr float SCALE_F = 0.17677669529663687f;  // 32^-0.5

// ---------- lengths[b] = sum(mask[b,:]) ----------
__global__ __launch_bounds__(256) void len_kernel(const int* __restrict__ mask,
                                                  int* __restrict__ len) {
  int b = blockIdx.x, t = threadIdx.x;
  int s = 0;
  for (int i = t; i < Sn; i += 256) s += mask[b * Sn + i];
#pragma unroll
  for (int off = 32; off > 0; off >>= 1) s += __shfl_down(s, off, 64);
  __shared__ int red[4];
  if ((t & 63) == 0) red[t >> 6] = s;
  __syncthreads();
  if (t == 0) len[b] = red[0] + red[1] + red[2] + red[3];
}

// ---------- tiled GEMM: C[M,N] = A[M,256] @ W[N,256]^T  (all fp32) ----------
template <int BM, int BN, int TM, int TN, int EPI>
__global__ __launch_bounds__(256) void gemm_k(
    const float* __restrict__ Ap,
    const float* __restrict__ W0,
    const float* __restrict__ W1,
    const float* __restrict__ W2,
    float* __restrict__ O0, float* __restrict__ O1, float* __restrict__ O2,
    float* __restrict__ Oout) {
  constexpr int BK = 32;
  __shared__ __align__(16) float As[BK][BM + 4];
  __shared__ __align__(16) float Bs[BK][BN + 4];
  const int tid = threadIdx.x;
  const int j0 = blockIdx.x * BN;
  const int i0 = blockIdx.y * BM;

  const float* Wp;
  int jc0;
  if constexpr (EPI == 0) {
    const int mat = j0 >> 8;
    Wp = (mat == 0) ? W0 : ((mat == 1) ? W1 : W2);
    jc0 = j0 & 255;
  } else {
    Wp = W0;
    jc0 = j0;
  }

  float acc[TM][TN];
#pragma unroll
  for (int ii = 0; ii < TM; ++ii)
#pragma unroll
    for (int jj = 0; jj < TN; ++jj) acc[ii][jj] = 0.f;

  for (int k0 = 0; k0 < KD; k0 += BK) {
#pragma unroll
    for (int it = 0; it < (BM * BK / 4) / 256; ++it) {
      int c4 = tid + it * 256;
      int row = c4 >> 3, kk4 = (c4 & 7) * 4;
      float4 v = *(const float4*)&Ap[(size_t)(i0 + row) * KD + k0 + kk4];
      As[kk4 + 0][row] = v.x; As[kk4 + 1][row] = v.y;
      As[kk4 + 2][row] = v.z; As[kk4 + 3][row] = v.w;
    }
#pragma unroll
    for (int it = 0; it < (BN * BK / 4) / 256; ++it) {
      int c4 = tid + it * 256;
      int row = c4 >> 3, kk4 = (c4 & 7) * 4;
      float4 v = *(const float4*)&Wp[(size_t)(jc0 + row) * KD + k0 + kk4];
      Bs[kk4 + 0][row] = v.x; Bs[kk4 + 1][row] = v.y;
      Bs[kk4 + 2][row] = v.z; Bs[kk4 + 3][row] = v.w;
    }
    __syncthreads();
    {
      const int tx = tid & 15, ty = tid >> 4;
#pragma unroll
      for (int kk = 0; kk < BK; ++kk) {
        float a[TM], bb[TN];
#pragma unroll
        for (int ii = 0; ii < TM; ++ii) a[ii] = As[kk][ty * TM + ii];
#pragma unroll
        for (int jj = 0; jj < TN; ++jj) bb[jj] = Bs[kk][tx * TN + jj];
#pragma unroll
        for (int ii = 0; ii < TM; ++ii)
#pragma unroll
          for (int jj = 0; jj < TN; ++jj)
            acc[ii][jj] = fmaf(a[ii], bb[jj], acc[ii][jj]);
      }
    }
    __syncthreads();
  }

  const int tx = tid & 15, ty = tid >> 4;
  if constexpr (EPI == 0) {
    const int mat = j0 >> 8;
    float* obase = (mat == 0) ? O0 : ((mat == 1) ? O1 : O2);
    const float scale = (mat == 0) ? SCALE_F : 1.0f;  // fold softmax scale into Q
#pragma unroll
    for (int ii = 0; ii < TM; ++ii) {
      int i = i0 + ty * TM + ii;
      int bb_ = i >> 11, s = i & (Sn - 1);
#pragma unroll
      for (int jj = 0; jj < TN; jj += 4) {
        int c = jc0 + tx * TN + jj;
        int h = c >> 5, d = c & 31;
        float4 v = make_float4(acc[ii][jj] * scale, acc[ii][jj + 1] * scale,
                               acc[ii][jj + 2] * scale, acc[ii][jj + 3] * scale);
        *(float4*)&obase[((size_t)(bb_ * Hn + h) * Sn + s) * Dn + d] = v;
      }
    }
  } else {
#pragma unroll
    for (int ii = 0; ii < TM; ++ii) {
      int i = i0 + ty * TM + ii;
#pragma unroll
      for (int jj = 0; jj < TN; jj += 4) {
        int j = j0 + tx * TN + jj;
        float4 v = make_float4(acc[ii][jj], acc[ii][jj + 1],
                               acc[ii][jj + 2], acc[ii][jj + 3]);
        *(float4*)&Oout[(size_t)i * En + j] = v;
      }
    }
  }
}

// ---------- flash attention: wave = 8 queries x 8 key-octets ----------
// lane (ql, ko): private (m,l,acc[32]) over keys {ko + 8j}; shfl-butterfly merge at end.
// Block: 256 thr = 4 waves = 32 queries. Global key-split x NS with partials.
// pacc[((b*H+h)*NS+split)*Sn + q][32], pml[...][2] = (m,l)
template <int NS>
__global__ __launch_bounds__(256, 4) void attn_kernel(
    const float* __restrict__ Qg, const float* __restrict__ Kg,
    const float* __restrict__ Vg, const int* __restrict__ len,
    float* __restrict__ pacc, float* __restrict__ pml) {
  const int split = blockIdx.x & (NS - 1);
  const int qg = blockIdx.x / NS;
  const int h = blockIdx.y, b = blockIdx.z;
  const int L = len[b];
  const int q0 = qg * 32;
  if (q0 >= L) return;                 // block-uniform exit
  const int chunk = ((L + NS * 64 - 1) / (NS * 64)) * 64;
  const int ks = split * chunk;
  if (ks >= L) return;
  const int ke = min(L, ks + chunk);

  const int tid = threadIdx.x;
  const int lane = tid & 63;
  const int wv = tid >> 6;             // wave 0..3
  const int ql = lane >> 3;            // query-in-wave 0..7
  const int ko = lane & 7;             // key octet 0..7
  const int q = q0 + wv * 8 + ql;      // < Sn always; masked vs L at store
  const size_t bh = (size_t)(b * Hn + h) * Sn;

  float qr[32];
  {
    const float4* qp = (const float4*)&Qg[(bh + q) * Dn];
#pragma unroll
    for (int i = 0; i < 8; ++i) {
      float4 v = qp[i];
      qr[i * 4 + 0] = v.x; qr[i * 4 + 1] = v.y;
      qr[i * 4 + 2] = v.z; qr[i * 4 + 3] = v.w;
    }
  }

  __shared__ __align__(16) float Kld[64][36];  // stride 36: conflict-free reads
  __shared__ __align__(16) float Vld[64][36];

  float m = -1.0e30f, l = 0.f;
  float acc[32];
#pragma unroll
  for (int d = 0; d < 32; ++d) acc[d] = 0.f;

  for (int k0 = ks; k0 < ke; k0 += 64) {
    const int nk = min(64, ke - k0);
    __syncthreads();
#pragma unroll
    for (int it = 0; it < 2; ++it) {   // 256 thr stage 64x32 K and V tiles
      int f4 = tid + it * 256;
      int row = f4 >> 3, c4 = (f4 & 7) * 4;
      if (row < nk) {
        *(float4*)&Kld[row][c4] = *(const float4*)&Kg[(bh + k0 + row) * Dn + c4];
        *(float4*)&Vld[row][c4] = *(const float4*)&Vg[(bh + k0 + row) * Dn + c4];
      } else {                          // zero-fill tail rows: no stale NaN
        *(float4*)&Kld[row][c4] = make_float4(0.f, 0.f, 0.f, 0.f);
        *(float4*)&Vld[row][c4] = make_float4(0.f, 0.f, 0.f, 0.f);
      }
    }
    __syncthreads();

    // this lane's 8 keys: rows ko + 8j  (8 consecutive rows across octet-lanes per j)
    float s[8];
#pragma unroll
    for (int j = 0; j < 8; ++j) s[j] = 0.f;
#pragma unroll
    for (int i = 0; i < 8; ++i) {
      const float qx = qr[i * 4 + 0], qy = qr[i * 4 + 1];
      const float qz = qr[i * 4 + 2], qw = qr[i * 4 + 3];
#pragma unroll
      for (int j = 0; j < 8; ++j) {
        float4 kv = *(const float4*)&Kld[ko + 8 * j][i * 4];
        s[j] = fmaf(qx, kv.x, s[j]);
        s[j] = fmaf(qy, kv.y, s[j]);
        s[j] = fmaf(qz, kv.z, s[j]);
        s[j] = fmaf(qw, kv.w, s[j]);
      }
    }
#pragma unroll
    for (int j = 0; j < 8; ++j)
      if (ko + 8 * j >= nk) s[j] = -3.0e38f;   // masked key

    float m01 = fmaxf(s[0], s[1]), m23 = fmaxf(s[2], s[3]);
    float m45 = fmaxf(s[4], s[5]), m67 = fmaxf(s[6], s[7]);
    float m8 = fmaxf(fmaxf(m01, m23), fmaxf(m45, m67));
    float nm = fmaxf(m, m8);
    float p[8];
#pragma unroll
    for (int j = 0; j < 8; ++j) p[j] = __expf(s[j] - nm);  // masked -> 0
    float sc = __expf(m - nm);
    float psum = ((p[0] + p[1]) + (p[2] + p[3])) + ((p[4] + p[5]) + (p[6] + p[7]));
    l = l * sc + psum;
    m = nm;
#pragma unroll
    for (int i = 0; i < 8; ++i) {
      float ax = acc[i * 4 + 0] * sc, ay = acc[i * 4 + 1] * sc;
      float az = acc[i * 4 + 2] * sc, aw = acc[i * 4 + 3] * sc;
#pragma unroll
      for (int j = 0; j < 8; ++j) {
        float4 vv = *(const float4*)&Vld[ko + 8 * j][i * 4];
        ax = fmaf(p[j], vv.x, ax);
        ay = fmaf(p[j], vv.y, ay);
        az = fmaf(p[j], vv.z, az);
        aw = fmaf(p[j], vv.w, aw);
      }
      acc[i * 4 + 0] = ax; acc[i * 4 + 1] = ay;
      acc[i * 4 + 2] = az; acc[i * 4 + 3] = aw;
    }
  }

  // ---- merge 8 key-octets within each query group (lane bits 0..2) ----
#pragma unroll
  for (int mask = 1; mask <= 4; mask <<= 1) {
    float mo = __shfl_xor(m, mask, 64);
    float lo = __shfl_xor(l, mask, 64);
    float nm = fmaxf(m, mo);
    float sa = __expf(m - nm);
    float sb = __expf(mo - nm);
    l = l * sa + lo * sb;
#pragma unroll
    for (int d = 0; d < 32; ++d) {
      float ao = __shfl_xor(acc[d], mask, 64);
      acc[d] = acc[d] * sa + ao * sb;
    }
    m = nm;
  }

  if (q < L) {
    const size_t idx = ((size_t)(b * Hn + h) * NS + split) * Sn + q;
    // lane ko writes float4 chunk #ko of the 32-float acc (coalesced 128B per query)
    float4 v = make_float4(acc[0], acc[1], acc[2], acc[3]);
#pragma unroll
    for (int i = 1; i < 8; ++i)
      if (ko == i) v = make_float4(acc[4 * i], acc[4 * i + 1],
                                   acc[4 * i + 2], acc[4 * i + 3]);
    *(float4*)&pacc[idx * 32 + ko * 4] = v;
    if (ko == 0) *(float2*)&pml[idx * 2] = make_float2(m, l);
  }
}

// ---------- merge key-splits, write scrambled P: P[b].flat[h*L*D + q*D + d] ----------
template <int NS>
__global__ __launch_bounds__(256) void combine_kernel(const float* __restrict__ pacc,
                                                      const float* __restrict__ pml,
                                                      const int* __restrict__ len,
                                                      float* __restrict__ P) {
  const int h = blockIdx.y, b = blockIdx.z;
  const int L = len[b];
  const int q = blockIdx.x * 256 + threadIdx.x;
  if (q >= L) return;
  const int chunk = ((L + NS * 64 - 1) / (NS * 64)) * 64;
  const size_t base = (size_t)(b * Hn + h) * NS * Sn;

  float M = -INFINITY;
  int ns = 0;
  float ms[NS], ls[NS];
#pragma unroll
  for (int sp = 0; sp < NS; ++sp) {
    if (sp * chunk < L) {
      float2 ml = *(const float2*)&pml[(base + (size_t)sp * Sn + q) * 2];
      ms[sp] = ml.x; ls[sp] = ml.y;
      M = fmaxf(M, ml.x);
      ns = sp + 1;
    }
  }
  float T = 0.f;
  float o[32];
#pragma unroll
  for (int d = 0; d < 32; ++d) o[d] = 0.f;
  for (int sp = 0; sp < ns; ++sp) {
    float w = __expf(ms[sp] - M);
    T += ls[sp] * w;
    const float4* pp = (const float4*)&pacc[(base + (size_t)sp * Sn + q) * 32];
#pragma unroll
    for (int i = 0; i < 8; ++i) {
      float4 v = pp[i];
      o[i * 4 + 0] = fmaf(w, v.x, o[i * 4 + 0]);
      o[i * 4 + 1] = fmaf(w, v.y, o[i * 4 + 1]);
      o[i * 4 + 2] = fmaf(w, v.z, o[i * 4 + 2]);
      o[i * 4 + 3] = fmaf(w, v.w, o[i * 4 + 3]);
    }
  }
  const float inv = 1.0f / T;
  float* dst = &P[(size_t)b * Sn * En + (size_t)h * L * Dn + (size_t)q * Dn];
#pragma unroll
  for (int i = 0; i < 8; ++i) {
    float4 v = make_float4(o[i * 4] * inv, o[i * 4 + 1] * inv,
                           o[i * 4 + 2] * inv, o[i * 4 + 3] * inv);
    *(float4*)&dst[i * 4] = v;
  }
}

// ---------- zero P tail [L*E, S*E) per batch ----------
__global__ __launch_bounds__(256) void ztail_kernel(const int* __restrict__ len,
                                                    float* __restrict__ P) {
  const int b = blockIdx.y;
  const int L = len[b];
  const int idx = (blockIdx.x * 256 + threadIdx.x) * 4;
  if (idx >= L * En)
    *(float4*)&P[(size_t)b * Sn * En + idx] = make_float4(0.f, 0.f, 0.f, 0.f);
}

extern "C" void kernel_launch(void* const* d_in, const int* in_sizes, int n_in,
                              void* d_out, int out_size, void* d_ws, size_t ws_size,
                              hipStream_t stream) {
  (void)in_sizes; (void)n_in; (void)out_size; (void)ws_size;
  const float* x  = (const float*)d_in[0];  // fp32 (B,S,E)
  const int* mask = (const int*)d_in[1];    // int32 (B,S)
  const float* Wq = (const float*)d_in[2];  // fp32 (E,E)
  const float* Wk = (const float*)d_in[3];
  const float* Wv = (const float*)d_in[4];
  const float* Wo = (const float*)d_in[5];
  float* out = (float*)d_out;               // fp32 (B,S,E)

  // workspace (fp32): lengths | Q | K | V | P | pacc | pml   (~69 MB, proven size)
  float* wsf = (float*)d_ws;
  int* lengths = (int*)d_ws;
  const size_t BHSD = (size_t)Bn * Hn * Sn * Dn;  // 2,097,152
  float* Qw = wsf + 64;
  float* Kw = Qw + BHSD;
  float* Vw = Kw + BHSD;
  float* Pw = Vw + BHSD;
  float* pacc = Pw + (size_t)Bn * Sn * En;
  constexpr int NS = 4;
  float* pml = pacc + (size_t)Bn * Hn * NS * Sn * 32;

  len_kernel<<<dim3(Bn), 256, 0, stream>>>(mask, lengths);
  gemm_k<128, 128, 8, 8, 0><<<dim3(6, 64), 256, 0, stream>>>(
      x, Wq, Wk, Wv, Qw, Kw, Vw, nullptr);
  attn_kernel<NS><<<dim3((Sn / 32) * NS, Hn, Bn), 256, 0, stream>>>(
      Qw, Kw, Vw, lengths, pacc, pml);
  combine_kernel<NS><<<dim3(Sn / 256, Hn, Bn), 256, 0, stream>>>(
      pacc, pml, lengths, Pw);
  ztail_kernel<<<dim3(Sn * En / 1024, Bn), 256, 0, stream>>>(lengths, Pw);
  gemm_k<64, 128, 4, 8, 1><<<dim3(2, 128), 256, 0, stream>>>(
      Pw, Wo, Wo, Wo, nullptr, nullptr, nullptr, out);
}